// Round 5
// baseline (152.794 us; speedup 1.0000x reference)
//
#include <hip/hip_runtime.h>
#include <hip/hip_bf16.h>

#define ALPHA 0.2f

typedef __attribute__((ext_vector_type(8))) short short8;
typedef __attribute__((ext_vector_type(4))) short s4;
typedef __attribute__((ext_vector_type(8))) _Float16 h8;
typedef __attribute__((ext_vector_type(2))) _Float16 h2v;
typedef __attribute__((ext_vector_type(4))) float f32x4;
typedef __attribute__((ext_vector_type(2))) short sh2;

static constexpr int B = 4, N = 2048, F = 256, H = 8, D = 32;
static constexpr int SZ_X = B * N * F, SZ_ADJ = B * N * N, SZ_W = H * F * D, SZ_A = H * 2 * D;
static const float C1 = 1.4426950408889634f;           // log2(e)
static const float C2 = ALPHA * 1.4426950408889634f;

// ws layout (bytes):
// 0        WT2  bf16 [kc=8][hd=256][32] 131072   (B-frag-contiguous W)
// 131072   AF   f32  [H][64]            2048
// 133120   S1   f32  [32][2048]         262144
// 395264   UH   f16  [32][2048]         131072
// 526336   VH   f16  [32][2048]         131072
// 657408   WHT  f16  [b][hd=256][2048]  4194304
// 4851712  BM   u64  [B*N*N/64]         2097152   total ~6.6 MB

__device__ __forceinline__ unsigned rne16(unsigned u) {
    return u + 0x7fffu + ((u >> 16) & 1u);
}
__device__ __forceinline__ unsigned pk_rne(float a, float b) {   // bf16 pair
    return __builtin_amdgcn_perm(rne16(__float_as_uint(b)),
                                 rne16(__float_as_uint(a)), 0x07060302u);
}
__device__ __forceinline__ unsigned h2mul(unsigned a, unsigned b) {
    h2v r = __builtin_bit_cast(h2v, a) * __builtin_bit_cast(h2v, b);
    return __builtin_bit_cast(unsigned, r);
}
__device__ __forceinline__ unsigned h2max(unsigned a, unsigned b) {
    h2v r = __builtin_elementwise_max(__builtin_bit_cast(h2v, a),
                                      __builtin_bit_cast(h2v, b));
    return __builtin_bit_cast(unsigned, r);
}
__device__ __forceinline__ unsigned dup16f(float x) {
    unsigned short w = __builtin_bit_cast(unsigned short, (_Float16)x);
    return (unsigned)w | ((unsigned)w << 16);
}
// bits (0,1) of mk -> {0xFFFF,0} half-masks: v_and + v_mul_lo + v_pk_ashrrev_i16
__device__ __forceinline__ unsigned bits2mask(unsigned mk, unsigned mulc) {
    unsigned w = (mk & 3u) * mulc;          // b0 -> bit 15 ; b1 -> bit 31
    sh2 s = __builtin_bit_cast(sh2, w);
    s = s >> 15;                            // smear each 16-bit half from its sign bit
    return __builtin_bit_cast(unsigned, s);
}

// ---- k0: W[h][f][d] -> WT2[f>>5][h*32+d][f&31] bf16; a -> AF --------------
__global__ void k0_prep(const float* __restrict__ Wp, const float* __restrict__ ap,
                        unsigned short* __restrict__ WT2, float* __restrict__ AF) {
    int bid = blockIdx.x;              // 256 = H*D
    int h = bid >> 5, d = bid & 31;
    int f = threadIdx.x;
    unsigned short v = (unsigned short)(rne16(__float_as_uint(Wp[(h * F + f) * D + d])) >> 16);
    WT2[(size_t)(f >> 5) * 8192 + (h * 32 + d) * 32 + (f & 31)] = v;
    if (d == 0 && f < 64) AF[h * 64 + f] = ap[h * 64 + f];
}

// ---- k2: fused {Wh MFMA blocks} + {adj->bitmask blocks}; role by bid%5 ----
__global__ __launch_bounds__(256, 4) void k2_fused(const float* __restrict__ x,
                                                   const unsigned short* __restrict__ WT2,
                                                   const float* __restrict__ AF,
                                                   unsigned short* __restrict__ WHT,
                                                   float* __restrict__ S1,
                                                   _Float16* __restrict__ UH,
                                                   _Float16* __restrict__ VH,
                                                   const int* __restrict__ adj,
                                                   unsigned long long* __restrict__ bm) {
    __shared__ unsigned short XA[16 * 264];   // [n][f] bf16, stride 264 (528B, /16 ok)
    int bid = blockIdx.x;                     // 2560 = 512 mfma + 2048 bitmask, interleaved
    int rr = bid % 5;
    int grp = bid / 5;
    int t = threadIdx.x;

    if (rr != 4) {
        // ---- bitmask role: 32 strips/wave, all 32 loads in flight ----
        int wid = (grp * 4 + rr) * 4 + (t >> 6);   // 8192 wids x 32 strips = 262144
        int lane = t & 63;
        size_t base = (size_t)wid * 32;
        const int* ap2 = adj + base * 64 + lane;
        int v0[16], v1[16];
#pragma unroll
        for (int s = 0; s < 16; s++) v0[s] = ap2[(size_t)s * 64];
#pragma unroll
        for (int s = 0; s < 16; s++) v1[s] = ap2[(size_t)(16 + s) * 64];
        unsigned long long m0[16];
#pragma unroll
        for (int s = 0; s < 16; s++) m0[s] = __ballot(v0[s] != 0);
        unsigned long long m1[16];
#pragma unroll
        for (int s = 0; s < 16; s++) m1[s] = __ballot(v1[s] != 0);
        if (lane == 0) {
#pragma unroll
            for (int s = 0; s < 16; s++) bm[base + s] = m0[s];
#pragma unroll
            for (int s = 0; s < 16; s++) bm[base + 16 + s] = m1[s];
        }
        return;
    }

    // ---- Wh MFMA role ----
    int b = grp >> 7;
    int n0 = (grp & 127) * 16;
    int wave = t >> 6, lane = t & 63;
    int lm = lane & 15, lq = lane >> 4;

    // stage XA coalesced: x fp32 -> bf16
#pragma unroll
    for (int q = 0; q < 4; q++) {
        int idx = q * 256 + t;
        int row = idx >> 6, c16 = idx & 63;
        f32x4 v = *(const f32x4*)(x + (size_t)(b * N + n0 + row) * F + c16 * 4);
        unsigned* dst = (unsigned*)&XA[row * 264 + c16 * 4];
        dst[0] = pk_rne(v[0], v[1]);
        dst[1] = pk_rne(v[2], v[3]);
    }

    // issue kc=0 B-frag loads before the barrier (independent of XA)
    short8 bcur[4], bnext[4];
#pragma unroll
    for (int c = 0; c < 4; c++)
        bcur[c] = *(const short8*)(WT2 + (size_t)(wave * 64 + c * 16 + lm) * 32 + lq * 8);
    __syncthreads();

    f32x4 acc[4] = {};
#pragma unroll
    for (int kc = 0; kc < 8; kc++) {
        if (kc < 7) {
#pragma unroll
            for (int c = 0; c < 4; c++)
                bnext[c] = *(const short8*)(WT2 + (size_t)(kc + 1) * 8192 +
                                            (wave * 64 + c * 16 + lm) * 32 + lq * 8);
        }
        short8 afr = *(const short8*)&XA[lm * 264 + kc * 32 + lq * 8];
#pragma unroll
        for (int c = 0; c < 4; c++)
            acc[c] = __builtin_amdgcn_mfma_f32_16x16x32_bf16(afr, bcur[c], acc[c], 0, 0, 0);
#pragma unroll
        for (int c = 0; c < 4; c++) bcur[c] = bnext[c];
    }

    // epilogue 1: WHT[b][hd][n] f16, 8B packed stores
#pragma unroll
    for (int c = 0; c < 4; c++) {
        int hd = wave * 64 + c * 16 + lm;
        unsigned short w0 = __builtin_bit_cast(unsigned short, (_Float16)acc[c][0]);
        unsigned short w1 = __builtin_bit_cast(unsigned short, (_Float16)acc[c][1]);
        unsigned short w2 = __builtin_bit_cast(unsigned short, (_Float16)acc[c][2]);
        unsigned short w3 = __builtin_bit_cast(unsigned short, (_Float16)acc[c][3]);
        uint2 pk;
        pk.x = (unsigned)w0 | ((unsigned)w1 << 16);
        pk.y = (unsigned)w2 | ((unsigned)w3 << 16);
        *(uint2*)&WHT[((size_t)b * 256 + hd) * 2048 + n0 + lq * 4] = pk;
    }
    // epilogue 2: s1/s2 -> S1/UH/VH
#pragma unroll
    for (int cp = 0; cp < 2; cp++) {
        int h = wave * 2 + cp;
        float a1l = AF[h * 64 + lm],      a1h = AF[h * 64 + 16 + lm];
        float a2l = AF[h * 64 + 32 + lm], a2h = AF[h * 64 + 48 + lm];
#pragma unroll
        for (int r = 0; r < 4; r++) {
            float s1p = acc[cp * 2][r] * a1l + acc[cp * 2 + 1][r] * a1h;
            float s2p = acc[cp * 2][r] * a2l + acc[cp * 2 + 1][r] * a2h;
#pragma unroll
            for (int off = 1; off <= 8; off <<= 1) {
                s1p += __shfl_xor(s1p, off);
                s2p += __shfl_xor(s2p, off);
            }
            if (lm == 0) {
                int bh = b * 8 + h, n = n0 + lq * 4 + r;
                S1[(size_t)bh * 2048 + n] = s1p;
                UH[(size_t)bh * 2048 + n] = (_Float16)exp2f(C1 * s2p);
                VH[(size_t)bh * 2048 + n] = (_Float16)exp2f(C2 * s2p);
            }
        }
    }
}

// ---- k3: block=(b,h,128-i tile); 4-buf LW pipeline; masks direct from L2 --
// No LM staging: LDS 35.8KB -> 4 blocks/CU (16 waves/CU). bm32 is 2MB,
// L2-resident; mask uint4 address is quad-invariant (broadcast within wave).
__global__ __launch_bounds__(256, 4) void k3_attn(
    const unsigned* __restrict__ bm32,
    const unsigned short* __restrict__ WHT,
    const float* __restrict__ S1,
    const _Float16* __restrict__ UH, const _Float16* __restrict__ VH,
    float* __restrict__ out) {
    __shared__ unsigned short LW[4][32 * 140];     // 4-buf [d][128j] (35840 B)

    // XCD-aware swizzle: group the 16 isup-blocks of one (b,h) on one XCD.
    int bid = blockIdx.x;                          // 512
    int bh = (bid & 7) + ((bid >> 7) << 3);
    int isup = (bid >> 3) & 15;
    int b = bh >> 3, h = bh & 7;
    int i0 = isup * 128;
    int t = threadIdx.x;
    int wave = t >> 6, lane = t & 63;
    int irow = lane & 15, quad = lane >> 4;
    int iw = i0 + wave * 32;                       // this wave's 32 i-rows

    // direct global mask rows (replaces LM LDS staging)
    const unsigned* bmA = bm32 + (size_t)(b * N + iw + irow) * 64;
    const unsigned* bmB = bm32 + (size_t)(b * N + iw + 16 + irow) * 64;

    const unsigned short* wsrc = WHT + ((size_t)b * 256 + h * 32) * 2048;
    int srow = t >> 3, sseg = (t & 7) * 16;        // staging map: 32B/thread/chunk

    // prologue: stage chunks 0,1
    {
        const unsigned short* g0 = wsrc + (size_t)srow * 2048 + sseg;
        union { short8 v; s4 q[2]; } a0, c0, a1, c1;
        a0.v = *(const short8*)(g0);
        c0.v = *(const short8*)(g0 + 8);
        a1.v = *(const short8*)(g0 + 128);
        c1.v = *(const short8*)(g0 + 136);
        unsigned short* d0 = &LW[0][srow * 140 + sseg];
        *(s4*)(d0) = a0.q[0]; *(s4*)(d0 + 4) = a0.q[1];
        *(s4*)(d0 + 8) = c0.q[0]; *(s4*)(d0 + 12) = c0.q[1];
        unsigned short* d1 = &LW[1][srow * 140 + sseg];
        *(s4*)(d1) = a1.q[0]; *(s4*)(d1 + 4) = a1.q[1];
        *(s4*)(d1 + 8) = c1.q[0]; *(s4*)(d1 + 12) = c1.q[1];
    }

    float s1A = S1[(size_t)bh * 2048 + iw + irow];
    float s1B = S1[(size_t)bh * 2048 + iw + 16 + irow];
    unsigned ci2A = dup16f(exp2f((C2 - C1) * s1A));
    unsigned ci2B = dup16f(exp2f((C2 - C1) * s1B));
    const _Float16* up = UH + (size_t)bh * 2048;
    const _Float16* vp = VH + (size_t)bh * 2048;

    union { h8 v; unsigned u[4]; } ones;
    ones.u[0] = ones.u[1] = ones.u[2] = ones.u[3] = 0x3C003C00u;

    const unsigned MUL = 0x40008000u;              // bit-deposit multiplier (SGPR)

    f32x4 aA0 = {0,0,0,0}, aA1 = {0,0,0,0}, aAL = {0,0,0,0};
    f32x4 aB0 = {0,0,0,0}, aB1 = {0,0,0,0}, aBL = {0,0,0,0};
    __syncthreads();

    for (int g = 0; g < 8; g++) {
        // prefetch chunks 2g+2, 2g+3 (consumed after 2 chunks of compute)
        union { short8 v; s4 q[2]; } pa0, pc0, pa1, pc1;
        if (g < 7) {
            const unsigned short* g0 = wsrc + (size_t)srow * 2048 + (2 * g + 2) * 128 + sseg;
            pa0.v = *(const short8*)(g0);
            pc0.v = *(const short8*)(g0 + 8);
            pa1.v = *(const short8*)(g0 + 128);
            pc1.v = *(const short8*)(g0 + 136);
        }
#pragma unroll
        for (int ci = 0; ci < 2; ci++) {
            int cc = 2 * g + ci;
            const unsigned short* lwp = LW[cc & 3];
            // mask words for this chunk: one uint4 per frag-row, straight from L2
            uint4 mkqA = *(const uint4*)(bmA + cc * 4);
            uint4 mkqB = *(const uint4*)(bmB + cc * 4);
            unsigned mkwA[4] = { mkqA.x, mkqA.y, mkqA.z, mkqA.w };
            unsigned mkwB[4] = { mkqB.x, mkqB.y, mkqB.z, mkqB.w };
#pragma unroll
            for (int ks = 0; ks < 4; ks++) {
                int jl = ks * 32 + quad * 8;
                int jg = cc * 128 + jl;
                uint4 uw = *(const uint4*)(up + jg);
                uint4 vw = *(const uint4*)(vp + jg);
                unsigned mkA = mkwA[ks] >> (quad * 8);
                unsigned mkB = mkwB[ks] >> (quad * 8);
                unsigned mA0 = bits2mask(mkA,      MUL);
                unsigned mA1 = bits2mask(mkA >> 2, MUL);
                unsigned mA2 = bits2mask(mkA >> 4, MUL);
                unsigned mA3 = bits2mask(mkA >> 6, MUL);
                unsigned mB0 = bits2mask(mkB,      MUL);
                unsigned mB1 = bits2mask(mkB >> 2, MUL);
                unsigned mB2 = bits2mask(mkB >> 4, MUL);
                unsigned mB3 = bits2mask(mkB >> 6, MUL);
                union { h8 v; unsigned u[4]; } afA, afB;
                afA.u[0] = h2max(uw.x, h2mul(ci2A, vw.x)) & mA0;
                afA.u[1] = h2max(uw.y, h2mul(ci2A, vw.y)) & mA1;
                afA.u[2] = h2max(uw.z, h2mul(ci2A, vw.z)) & mA2;
                afA.u[3] = h2max(uw.w, h2mul(ci2A, vw.w)) & mA3;
                afB.u[0] = h2max(uw.x, h2mul(ci2B, vw.x)) & mB0;
                afB.u[1] = h2max(uw.y, h2mul(ci2B, vw.y)) & mB1;
                afB.u[2] = h2max(uw.z, h2mul(ci2B, vw.z)) & mB2;
                afB.u[3] = h2max(uw.w, h2mul(ci2B, vw.w)) & mB3;
                union { short8 v; s4 q[2]; } bf0, bf1;
                bf0.q[0] = *(const s4*)&lwp[irow * 140 + jl];
                bf0.q[1] = *(const s4*)&lwp[irow * 140 + jl + 4];
                bf1.q[0] = *(const s4*)&lwp[(16 + irow) * 140 + jl];
                bf1.q[1] = *(const s4*)&lwp[(16 + irow) * 140 + jl + 4];
                h8 b0 = __builtin_bit_cast(h8, bf0.v);
                h8 b1 = __builtin_bit_cast(h8, bf1.v);
                aA0 = __builtin_amdgcn_mfma_f32_16x16x32_f16(afA.v, b0, aA0, 0, 0, 0);
                aA1 = __builtin_amdgcn_mfma_f32_16x16x32_f16(afA.v, b1, aA1, 0, 0, 0);
                aAL = __builtin_amdgcn_mfma_f32_16x16x32_f16(afA.v, ones.v, aAL, 0, 0, 0);
                aB0 = __builtin_amdgcn_mfma_f32_16x16x32_f16(afB.v, b0, aB0, 0, 0, 0);
                aB1 = __builtin_amdgcn_mfma_f32_16x16x32_f16(afB.v, b1, aB1, 0, 0, 0);
                aBL = __builtin_amdgcn_mfma_f32_16x16x32_f16(afB.v, ones.v, aBL, 0, 0, 0);
            }
        }
        if (g < 7) {
            // write into buffers last read in group g-1 (all waves past that barrier)
            unsigned short* d0 = &LW[(2 * g + 2) & 3][srow * 140 + sseg];
            *(s4*)(d0) = pa0.q[0]; *(s4*)(d0 + 4) = pa0.q[1];
            *(s4*)(d0 + 8) = pc0.q[0]; *(s4*)(d0 + 12) = pc0.q[1];
            unsigned short* d1 = &LW[(2 * g + 3) & 3][srow * 140 + sseg];
            *(s4*)(d1) = pa1.q[0]; *(s4*)(d1 + 4) = pa1.q[1];
            *(s4*)(d1 + 8) = pc1.q[0]; *(s4*)(d1 + 12) = pc1.q[1];
        }
        __syncthreads();
    }

#pragma unroll
    for (int r = 0; r < 4; r++) {
        float lA = aAL[r], lB = aBL[r];
        float rA = 1.0f / (lA > 0.f ? lA : 1.f);
        float rB = 1.0f / (lB > 0.f ? lB : 1.f);
        float vA0 = aA0[r] * rA, vA1 = aA1[r] * rA;
        float vB0 = aB0[r] * rB, vB1 = aB1[r] * rB;
        vA0 = vA0 > 0.f ? vA0 : __expf(vA0) - 1.f;   // ELU
        vA1 = vA1 > 0.f ? vA1 : __expf(vA1) - 1.f;
        vB0 = vB0 > 0.f ? vB0 : __expf(vB0) - 1.f;
        vB1 = vB1 > 0.f ? vB1 : __expf(vB1) - 1.f;
        int iA = iw + quad * 4 + r, iB = iA + 16;
        size_t rbA = (size_t)(b * N + iA) * 256 + h * 32;
        size_t rbB = (size_t)(b * N + iB) * 256 + h * 32;
        out[rbA + irow] = vA0;
        out[rbA + 16 + irow] = vA1;
        out[rbB + irow] = vB0;
        out[rbB + 16 + irow] = vB1;
    }
}

extern "C" void kernel_launch(void* const* d_in, const int* in_sizes, int n_in,
                              void* d_out, int out_size, void* d_ws, size_t ws_size,
                              hipStream_t stream) {
    const void *xP = nullptr, *adjP = nullptr, *WP = nullptr, *aP = nullptr;
    for (int i = 0; i < n_in; i++) {
        switch (in_sizes[i]) {
            case SZ_X:   xP = d_in[i]; break;
            case SZ_ADJ: adjP = d_in[i]; break;
            case SZ_W:   WP = d_in[i]; break;
            case SZ_A:   aP = d_in[i]; break;
            default: break;
        }
    }
    if (!xP || !adjP || !WP || !aP) { xP = d_in[0]; adjP = d_in[1]; WP = d_in[2]; aP = d_in[3]; }
    float* out = (float*)d_out;

    char* ws = (char*)d_ws;
    unsigned short* WT2 = (unsigned short*)(ws);
    float* AF  = (float*)(ws + 131072);
    float* S1  = (float*)(ws + 133120);
    _Float16* UH = (_Float16*)(ws + 395264);
    _Float16* VH = (_Float16*)(ws + 526336);
    unsigned short* WHT = (unsigned short*)(ws + 657408);
    unsigned long long* BM = (unsigned long long*)(ws + 4851712);

    k0_prep<<<256, 256, 0, stream>>>((const float*)WP, (const float*)aP, WT2, AF);
    k2_fused<<<2560, 256, 0, stream>>>((const float*)xP, WT2, AF, WHT, S1, UH, VH,
                                       (const int*)adjP, BM);
    k3_attn<<<512, 256, 0, stream>>>((const unsigned*)BM, WHT, S1, UH, VH, out);
}

// Round 6
// 146.049 us; speedup vs baseline: 1.0462x; 1.0462x over previous
//
#include <hip/hip_runtime.h>
#include <hip/hip_bf16.h>

#define ALPHA 0.2f

typedef __attribute__((ext_vector_type(8))) short short8;
typedef __attribute__((ext_vector_type(4))) short s4;
typedef __attribute__((ext_vector_type(8))) _Float16 h8;
typedef __attribute__((ext_vector_type(2))) _Float16 h2v;
typedef __attribute__((ext_vector_type(4))) float f32x4;
typedef __attribute__((ext_vector_type(2))) short sh2;

static constexpr int B = 4, N = 2048, F = 256, H = 8, D = 32;
static constexpr int SZ_X = B * N * F, SZ_ADJ = B * N * N, SZ_W = H * F * D, SZ_A = H * 2 * D;
static const float C1 = 1.4426950408889634f;           // log2(e)
static const float C2 = ALPHA * 1.4426950408889634f;

// ws layout (bytes):
// 0        WT2  bf16 [kc=8][hd=256][32] 131072   (B-frag-contiguous W)
// 131072   AF   f32  [H][64]            2048
// 133120   S1   f32  [32][2048]         262144
// 395264   UH   f16  [32][2048]         131072
// 526336   VH   f16  [32][2048]         131072
// 657408   WHT  f16  [b][hd=256][2048]  4194304
// 4851712  BM   u64  [B*N*N/64]         2097152   total ~6.6 MB

__device__ __forceinline__ unsigned rne16(unsigned u) {
    return u + 0x7fffu + ((u >> 16) & 1u);
}
__device__ __forceinline__ unsigned pk_rne(float a, float b) {   // bf16 pair
    return __builtin_amdgcn_perm(rne16(__float_as_uint(b)),
                                 rne16(__float_as_uint(a)), 0x07060302u);
}
__device__ __forceinline__ unsigned h2mul(unsigned a, unsigned b) {
    h2v r = __builtin_bit_cast(h2v, a) * __builtin_bit_cast(h2v, b);
    return __builtin_bit_cast(unsigned, r);
}
__device__ __forceinline__ unsigned h2max(unsigned a, unsigned b) {
    h2v r = __builtin_elementwise_max(__builtin_bit_cast(h2v, a),
                                      __builtin_bit_cast(h2v, b));
    return __builtin_bit_cast(unsigned, r);
}
__device__ __forceinline__ unsigned dup16f(float x) {
    unsigned short w = __builtin_bit_cast(unsigned short, (_Float16)x);
    return (unsigned)w | ((unsigned)w << 16);
}
// bits (0,1) of mk -> {0xFFFF,0} half-masks: v_and + v_mul_lo + v_pk_ashrrev_i16
__device__ __forceinline__ unsigned bits2mask(unsigned mk, unsigned mulc) {
    unsigned w = (mk & 3u) * mulc;          // b0 -> bit 15 ; b1 -> bit 31
    sh2 s = __builtin_bit_cast(sh2, w);
    s = s >> 15;                            // smear each 16-bit half from its sign bit
    return __builtin_bit_cast(unsigned, s);
}

// ---- k0: W[h][f][d] -> WT2[f>>5][h*32+d][f&31] bf16; a -> AF --------------
__global__ void k0_prep(const float* __restrict__ Wp, const float* __restrict__ ap,
                        unsigned short* __restrict__ WT2, float* __restrict__ AF) {
    int bid = blockIdx.x;              // 256 = H*D
    int h = bid >> 5, d = bid & 31;
    int f = threadIdx.x;
    unsigned short v = (unsigned short)(rne16(__float_as_uint(Wp[(h * F + f) * D + d])) >> 16);
    WT2[(size_t)(f >> 5) * 8192 + (h * 32 + d) * 32 + (f & 31)] = v;
    if (d == 0 && f < 64) AF[h * 64 + f] = ap[h * 64 + f];
}

// ---- k2: fused {Wh MFMA blocks} + {adj->bitmask blocks}; role by bid%5 ----
__global__ __launch_bounds__(256, 4) void k2_fused(const float* __restrict__ x,
                                                   const unsigned short* __restrict__ WT2,
                                                   const float* __restrict__ AF,
                                                   unsigned short* __restrict__ WHT,
                                                   float* __restrict__ S1,
                                                   _Float16* __restrict__ UH,
                                                   _Float16* __restrict__ VH,
                                                   const int* __restrict__ adj,
                                                   unsigned long long* __restrict__ bm) {
    __shared__ unsigned short XA[16 * 264];   // [n][f] bf16, stride 264 (528B, /16 ok)
    int bid = blockIdx.x;                     // 2560 = 512 mfma + 2048 bitmask, interleaved
    int rr = bid % 5;
    int grp = bid / 5;
    int t = threadIdx.x;

    if (rr != 4) {
        // ---- bitmask role: 32 strips/wave, all 32 loads in flight ----
        int wid = (grp * 4 + rr) * 4 + (t >> 6);   // 8192 wids x 32 strips = 262144
        int lane = t & 63;
        size_t base = (size_t)wid * 32;
        const int* ap2 = adj + base * 64 + lane;
        int v0[16], v1[16];
#pragma unroll
        for (int s = 0; s < 16; s++) v0[s] = ap2[(size_t)s * 64];
#pragma unroll
        for (int s = 0; s < 16; s++) v1[s] = ap2[(size_t)(16 + s) * 64];
        unsigned long long m0[16];
#pragma unroll
        for (int s = 0; s < 16; s++) m0[s] = __ballot(v0[s] != 0);
        unsigned long long m1[16];
#pragma unroll
        for (int s = 0; s < 16; s++) m1[s] = __ballot(v1[s] != 0);
        if (lane == 0) {
#pragma unroll
            for (int s = 0; s < 16; s++) bm[base + s] = m0[s];
#pragma unroll
            for (int s = 0; s < 16; s++) bm[base + 16 + s] = m1[s];
        }
        return;
    }

    // ---- Wh MFMA role ----
    int b = grp >> 7;
    int n0 = (grp & 127) * 16;
    int wave = t >> 6, lane = t & 63;
    int lm = lane & 15, lq = lane >> 4;

    // stage XA coalesced: x fp32 -> bf16
#pragma unroll
    for (int q = 0; q < 4; q++) {
        int idx = q * 256 + t;
        int row = idx >> 6, c16 = idx & 63;
        f32x4 v = *(const f32x4*)(x + (size_t)(b * N + n0 + row) * F + c16 * 4);
        unsigned* dst = (unsigned*)&XA[row * 264 + c16 * 4];
        dst[0] = pk_rne(v[0], v[1]);
        dst[1] = pk_rne(v[2], v[3]);
    }

    // issue kc=0 B-frag loads before the barrier (independent of XA)
    short8 bcur[4], bnext[4];
#pragma unroll
    for (int c = 0; c < 4; c++)
        bcur[c] = *(const short8*)(WT2 + (size_t)(wave * 64 + c * 16 + lm) * 32 + lq * 8);
    __syncthreads();

    f32x4 acc[4] = {};
#pragma unroll
    for (int kc = 0; kc < 8; kc++) {
        if (kc < 7) {
#pragma unroll
            for (int c = 0; c < 4; c++)
                bnext[c] = *(const short8*)(WT2 + (size_t)(kc + 1) * 8192 +
                                            (wave * 64 + c * 16 + lm) * 32 + lq * 8);
        }
        short8 afr = *(const short8*)&XA[lm * 264 + kc * 32 + lq * 8];
#pragma unroll
        for (int c = 0; c < 4; c++)
            acc[c] = __builtin_amdgcn_mfma_f32_16x16x32_bf16(afr, bcur[c], acc[c], 0, 0, 0);
#pragma unroll
        for (int c = 0; c < 4; c++) bcur[c] = bnext[c];
    }

    // epilogue 1: WHT[b][hd][n] f16, 8B packed stores
#pragma unroll
    for (int c = 0; c < 4; c++) {
        int hd = wave * 64 + c * 16 + lm;
        unsigned short w0 = __builtin_bit_cast(unsigned short, (_Float16)acc[c][0]);
        unsigned short w1 = __builtin_bit_cast(unsigned short, (_Float16)acc[c][1]);
        unsigned short w2 = __builtin_bit_cast(unsigned short, (_Float16)acc[c][2]);
        unsigned short w3 = __builtin_bit_cast(unsigned short, (_Float16)acc[c][3]);
        uint2 pk;
        pk.x = (unsigned)w0 | ((unsigned)w1 << 16);
        pk.y = (unsigned)w2 | ((unsigned)w3 << 16);
        *(uint2*)&WHT[((size_t)b * 256 + hd) * 2048 + n0 + lq * 4] = pk;
    }
    // epilogue 2: s1/s2 -> S1/UH/VH
#pragma unroll
    for (int cp = 0; cp < 2; cp++) {
        int h = wave * 2 + cp;
        float a1l = AF[h * 64 + lm],      a1h = AF[h * 64 + 16 + lm];
        float a2l = AF[h * 64 + 32 + lm], a2h = AF[h * 64 + 48 + lm];
#pragma unroll
        for (int r = 0; r < 4; r++) {
            float s1p = acc[cp * 2][r] * a1l + acc[cp * 2 + 1][r] * a1h;
            float s2p = acc[cp * 2][r] * a2l + acc[cp * 2 + 1][r] * a2h;
#pragma unroll
            for (int off = 1; off <= 8; off <<= 1) {
                s1p += __shfl_xor(s1p, off);
                s2p += __shfl_xor(s2p, off);
            }
            if (lm == 0) {
                int bh = b * 8 + h, n = n0 + lq * 4 + r;
                S1[(size_t)bh * 2048 + n] = s1p;
                UH[(size_t)bh * 2048 + n] = (_Float16)exp2f(C1 * s2p);
                VH[(size_t)bh * 2048 + n] = (_Float16)exp2f(C2 * s2p);
            }
        }
    }
}

// ---- k3: 512 threads / 8 waves per block; 16 i-rows per wave --------------
// Same 512-block grid (one 128-row tile per block; WHT slice staged ONCE),
// but 2x waves/CU (16 waves = 4/SIMD) for latency hiding. LM restored.
// LDS = LM 34816 + LW 35840 = 70656 B -> 2 blocks/CU (grid-matched).
__global__ __launch_bounds__(512, 4) void k3_attn(
    const unsigned* __restrict__ bm32,
    const unsigned short* __restrict__ WHT,
    const float* __restrict__ S1,
    const _Float16* __restrict__ UH, const _Float16* __restrict__ VH,
    float* __restrict__ out) {
    __shared__ unsigned LM[8][16 * 68];            // per-wave 16-row bitmask (34816 B)
    __shared__ unsigned short LW[4][32 * 140];     // 4-buf [d][128j] (35840 B)

    // XCD-aware swizzle: group the 16 isup-blocks of one (b,h) on one XCD.
    int bid = blockIdx.x;                          // 512
    int bh = (bid & 7) + ((bid >> 7) << 3);
    int isup = (bid >> 3) & 15;
    int b = bh >> 3, h = bh & 7;
    int i0 = isup * 128;
    int t = threadIdx.x;
    int wave = t >> 6, lane = t & 63;
    int irow = lane & 15, quad = lane >> 4;
    int iw = i0 + wave * 16;                       // this wave's 16 i-rows

    // per-wave private bitmask staging (16 loads in flight, no barrier needed)
    {
        unsigned* lmp = LM[wave];
        const unsigned* src = bm32 + ((size_t)(b * N + iw)) * 64;
#pragma unroll
        for (int r = 0; r < 16; r++)
            lmp[r * 68 + lane] = src[(size_t)r * 64 + lane];
    }

    const unsigned short* wsrc = WHT + ((size_t)b * 256 + h * 32) * 2048;
    int srow = t >> 4, sseg = (t & 15) * 8;        // staging map: 16B/thread/chunk

    // prologue: stage chunks 0,1
    {
        const unsigned short* g0 = wsrc + (size_t)srow * 2048 + sseg;
        union { short8 v; s4 q[2]; } a0, a1;
        a0.v = *(const short8*)(g0);
        a1.v = *(const short8*)(g0 + 128);
        unsigned short* d0 = &LW[0][srow * 140 + sseg];
        *(s4*)(d0) = a0.q[0]; *(s4*)(d0 + 4) = a0.q[1];
        unsigned short* d1 = &LW[1][srow * 140 + sseg];
        *(s4*)(d1) = a1.q[0]; *(s4*)(d1 + 4) = a1.q[1];
    }

    float s1A = S1[(size_t)bh * 2048 + iw + irow];
    unsigned ci2A = dup16f(exp2f((C2 - C1) * s1A));
    const _Float16* up = UH + (size_t)bh * 2048;
    const _Float16* vp = VH + (size_t)bh * 2048;

    union { h8 v; unsigned u[4]; } ones;
    ones.u[0] = ones.u[1] = ones.u[2] = ones.u[3] = 0x3C003C00u;

    const unsigned MUL = 0x40008000u;              // bit-deposit multiplier (SGPR)

    f32x4 aA0 = {0,0,0,0}, aA1 = {0,0,0,0}, aAL = {0,0,0,0};
    __syncthreads();

    for (int g = 0; g < 8; g++) {
        // prefetch chunks 2g+2, 2g+3 (consumed after 2 chunks of compute)
        union { short8 v; s4 q[2]; } pa0, pa1;
        if (g < 7) {
            const unsigned short* g0 = wsrc + (size_t)srow * 2048 + (2 * g + 2) * 128 + sseg;
            pa0.v = *(const short8*)(g0);
            pa1.v = *(const short8*)(g0 + 128);
        }
        const unsigned* lmw = LM[wave];
#pragma unroll
        for (int ci = 0; ci < 2; ci++) {
            int cc = 2 * g + ci;
            const unsigned short* lwp = LW[cc & 3];
            // all 4 mask words for this chunk: one b128 LDS read
            uint4 mkq = *(const uint4*)&lmw[irow * 68 + cc * 4];
            unsigned mkw[4] = { mkq.x, mkq.y, mkq.z, mkq.w };
#pragma unroll
            for (int ks = 0; ks < 4; ks++) {
                int jl = ks * 32 + quad * 8;
                int jg = cc * 128 + jl;
                uint4 uw = *(const uint4*)(up + jg);
                uint4 vw = *(const uint4*)(vp + jg);
                unsigned mkA = mkw[ks] >> (quad * 8);
                unsigned mA0 = bits2mask(mkA,      MUL);
                unsigned mA1 = bits2mask(mkA >> 2, MUL);
                unsigned mA2 = bits2mask(mkA >> 4, MUL);
                unsigned mA3 = bits2mask(mkA >> 6, MUL);
                union { h8 v; unsigned u[4]; } afA;
                afA.u[0] = h2max(uw.x, h2mul(ci2A, vw.x)) & mA0;
                afA.u[1] = h2max(uw.y, h2mul(ci2A, vw.y)) & mA1;
                afA.u[2] = h2max(uw.z, h2mul(ci2A, vw.z)) & mA2;
                afA.u[3] = h2max(uw.w, h2mul(ci2A, vw.w)) & mA3;
                union { short8 v; s4 q[2]; } bf0, bf1;
                bf0.q[0] = *(const s4*)&lwp[irow * 140 + jl];
                bf0.q[1] = *(const s4*)&lwp[irow * 140 + jl + 4];
                bf1.q[0] = *(const s4*)&lwp[(16 + irow) * 140 + jl];
                bf1.q[1] = *(const s4*)&lwp[(16 + irow) * 140 + jl + 4];
                h8 b0 = __builtin_bit_cast(h8, bf0.v);
                h8 b1 = __builtin_bit_cast(h8, bf1.v);
                aA0 = __builtin_amdgcn_mfma_f32_16x16x32_f16(afA.v, b0, aA0, 0, 0, 0);
                aA1 = __builtin_amdgcn_mfma_f32_16x16x32_f16(afA.v, b1, aA1, 0, 0, 0);
                aAL = __builtin_amdgcn_mfma_f32_16x16x32_f16(afA.v, ones.v, aAL, 0, 0, 0);
            }
        }
        if (g < 7) {
            // write into buffers last read in group g-1 (all waves past that barrier)
            unsigned short* d0 = &LW[(2 * g + 2) & 3][srow * 140 + sseg];
            *(s4*)(d0) = pa0.q[0]; *(s4*)(d0 + 4) = pa0.q[1];
            unsigned short* d1 = &LW[(2 * g + 3) & 3][srow * 140 + sseg];
            *(s4*)(d1) = pa1.q[0]; *(s4*)(d1 + 4) = pa1.q[1];
        }
        __syncthreads();
    }

#pragma unroll
    for (int r = 0; r < 4; r++) {
        float lA = aAL[r];
        float rA = 1.0f / (lA > 0.f ? lA : 1.f);
        float vA0 = aA0[r] * rA, vA1 = aA1[r] * rA;
        vA0 = vA0 > 0.f ? vA0 : __expf(vA0) - 1.f;   // ELU
        vA1 = vA1 > 0.f ? vA1 : __expf(vA1) - 1.f;
        int iA = iw + quad * 4 + r;
        size_t rbA = (size_t)(b * N + iA) * 256 + h * 32;
        out[rbA + irow] = vA0;
        out[rbA + 16 + irow] = vA1;
    }
}

extern "C" void kernel_launch(void* const* d_in, const int* in_sizes, int n_in,
                              void* d_out, int out_size, void* d_ws, size_t ws_size,
                              hipStream_t stream) {
    const void *xP = nullptr, *adjP = nullptr, *WP = nullptr, *aP = nullptr;
    for (int i = 0; i < n_in; i++) {
        switch (in_sizes[i]) {
            case SZ_X:   xP = d_in[i]; break;
            case SZ_ADJ: adjP = d_in[i]; break;
            case SZ_W:   WP = d_in[i]; break;
            case SZ_A:   aP = d_in[i]; break;
            default: break;
        }
    }
    if (!xP || !adjP || !WP || !aP) { xP = d_in[0]; adjP = d_in[1]; WP = d_in[2]; aP = d_in[3]; }
    float* out = (float*)d_out;

    char* ws = (char*)d_ws;
    unsigned short* WT2 = (unsigned short*)(ws);
    float* AF  = (float*)(ws + 131072);
    float* S1  = (float*)(ws + 133120);
    _Float16* UH = (_Float16*)(ws + 395264);
    _Float16* VH = (_Float16*)(ws + 526336);
    unsigned short* WHT = (unsigned short*)(ws + 657408);
    unsigned long long* BM = (unsigned long long*)(ws + 4851712);

    k0_prep<<<256, 256, 0, stream>>>((const float*)WP, (const float*)aP, WT2, AF);
    k2_fused<<<2560, 256, 0, stream>>>((const float*)xP, WT2, AF, WHT, S1, UH, VH,
                                       (const int*)adjP, BM);
    k3_attn<<<512, 512, 0, stream>>>((const unsigned*)BM, WHT, S1, UH, VH, out);
}

// Round 7
// 141.854 us; speedup vs baseline: 1.0771x; 1.0296x over previous
//
#include <hip/hip_runtime.h>
#include <hip/hip_bf16.h>

#define ALPHA 0.2f

typedef __attribute__((ext_vector_type(8))) short short8;
typedef __attribute__((ext_vector_type(4))) short s4;
typedef __attribute__((ext_vector_type(8))) _Float16 h8;
typedef __attribute__((ext_vector_type(2))) _Float16 h2v;
typedef __attribute__((ext_vector_type(4))) float f32x4;
typedef __attribute__((ext_vector_type(2))) short sh2;

static constexpr int B = 4, N = 2048, F = 256, H = 8, D = 32;
static constexpr int SZ_X = B * N * F, SZ_ADJ = B * N * N, SZ_W = H * F * D, SZ_A = H * 2 * D;
static const float C1 = 1.4426950408889634f;           // log2(e)
static const float C2 = ALPHA * 1.4426950408889634f;

// ws layout (bytes):
// 0        WT2  bf16 [kc=8][hd=256][32] 131072   (B-frag-contiguous W)
// 131072   AF   f32  [H][64]            2048
// 133120   S1   f32  [32][2048]         262144
// 395264   UH   f16  [32][2048]         131072
// 526336   VH   f16  [32][2048]         131072
// 657408   WHT  f16  [b][hd=256][2048]  4194304
// 4851712  BM   u64  [B*N*N/64]         2097152   total ~6.6 MB

__device__ __forceinline__ unsigned rne16(unsigned u) {
    return u + 0x7fffu + ((u >> 16) & 1u);
}
__device__ __forceinline__ unsigned pk_rne(float a, float b) {   // bf16 pair
    return __builtin_amdgcn_perm(rne16(__float_as_uint(b)),
                                 rne16(__float_as_uint(a)), 0x07060302u);
}
__device__ __forceinline__ unsigned h2mul(unsigned a, unsigned b) {
    h2v r = __builtin_bit_cast(h2v, a) * __builtin_bit_cast(h2v, b);
    return __builtin_bit_cast(unsigned, r);
}
__device__ __forceinline__ unsigned h2max(unsigned a, unsigned b) {
    h2v r = __builtin_elementwise_max(__builtin_bit_cast(h2v, a),
                                      __builtin_bit_cast(h2v, b));
    return __builtin_bit_cast(unsigned, r);
}
__device__ __forceinline__ unsigned dup16f(float x) {
    unsigned short w = __builtin_bit_cast(unsigned short, (_Float16)x);
    return (unsigned)w | ((unsigned)w << 16);
}
// bits (0,1) of mk -> {0xFFFF,0} half-masks: v_and + v_mul_lo + v_pk_ashrrev_i16
__device__ __forceinline__ unsigned bits2mask(unsigned mk, unsigned mulc) {
    unsigned w = (mk & 3u) * mulc;          // b0 -> bit 15 ; b1 -> bit 31
    sh2 s = __builtin_bit_cast(sh2, w);
    s = s >> 15;                            // smear each 16-bit half from its sign bit
    return __builtin_bit_cast(unsigned, s);
}

// ---- k0: W[h][f][d] -> WT2[f>>5][h*32+d][f&31] bf16; a -> AF --------------
__global__ void k0_prep(const float* __restrict__ Wp, const float* __restrict__ ap,
                        unsigned short* __restrict__ WT2, float* __restrict__ AF) {
    int bid = blockIdx.x;              // 256 = H*D
    int h = bid >> 5, d = bid & 31;
    int f = threadIdx.x;
    unsigned short v = (unsigned short)(rne16(__float_as_uint(Wp[(h * F + f) * D + d])) >> 16);
    WT2[(size_t)(f >> 5) * 8192 + (h * 32 + d) * 32 + (f & 31)] = v;
    if (d == 0 && f < 64) AF[h * 64 + f] = ap[h * 64 + f];
}

// ---- k2: fused {Wh MFMA blocks} + {adj->bitmask blocks}; role by bid%5 ----
__global__ __launch_bounds__(256, 4) void k2_fused(const float* __restrict__ x,
                                                   const unsigned short* __restrict__ WT2,
                                                   const float* __restrict__ AF,
                                                   unsigned short* __restrict__ WHT,
                                                   float* __restrict__ S1,
                                                   _Float16* __restrict__ UH,
                                                   _Float16* __restrict__ VH,
                                                   const int* __restrict__ adj,
                                                   unsigned long long* __restrict__ bm) {
    __shared__ unsigned short XA[16 * 264];   // [n][f] bf16, stride 264 (528B, /16 ok)
    int bid = blockIdx.x;                     // 2560 = 512 mfma + 2048 bitmask, interleaved
    int rr = bid % 5;
    int grp = bid / 5;
    int t = threadIdx.x;

    if (rr != 4) {
        // ---- bitmask role: 32 strips/wave, all 32 loads in flight ----
        int wid = (grp * 4 + rr) * 4 + (t >> 6);   // 8192 wids x 32 strips = 262144
        int lane = t & 63;
        size_t base = (size_t)wid * 32;
        const int* ap2 = adj + base * 64 + lane;
        int v0[16], v1[16];
#pragma unroll
        for (int s = 0; s < 16; s++) v0[s] = ap2[(size_t)s * 64];
#pragma unroll
        for (int s = 0; s < 16; s++) v1[s] = ap2[(size_t)(16 + s) * 64];
        unsigned long long m0[16];
#pragma unroll
        for (int s = 0; s < 16; s++) m0[s] = __ballot(v0[s] != 0);
        unsigned long long m1[16];
#pragma unroll
        for (int s = 0; s < 16; s++) m1[s] = __ballot(v1[s] != 0);
        if (lane == 0) {
#pragma unroll
            for (int s = 0; s < 16; s++) bm[base + s] = m0[s];
#pragma unroll
            for (int s = 0; s < 16; s++) bm[base + 16 + s] = m1[s];
        }
        return;
    }

    // ---- Wh MFMA role ----
    int b = grp >> 7;
    int n0 = (grp & 127) * 16;
    int wave = t >> 6, lane = t & 63;
    int lm = lane & 15, lq = lane >> 4;

    // stage XA coalesced: x fp32 -> bf16
#pragma unroll
    for (int q = 0; q < 4; q++) {
        int idx = q * 256 + t;
        int row = idx >> 6, c16 = idx & 63;
        f32x4 v = *(const f32x4*)(x + (size_t)(b * N + n0 + row) * F + c16 * 4);
        unsigned* dst = (unsigned*)&XA[row * 264 + c16 * 4];
        dst[0] = pk_rne(v[0], v[1]);
        dst[1] = pk_rne(v[2], v[3]);
    }

    // issue kc=0 B-frag loads before the barrier (independent of XA)
    short8 bcur[4], bnext[4];
#pragma unroll
    for (int c = 0; c < 4; c++)
        bcur[c] = *(const short8*)(WT2 + (size_t)(wave * 64 + c * 16 + lm) * 32 + lq * 8);
    __syncthreads();

    f32x4 acc[4] = {};
#pragma unroll
    for (int kc = 0; kc < 8; kc++) {
        if (kc < 7) {
#pragma unroll
            for (int c = 0; c < 4; c++)
                bnext[c] = *(const short8*)(WT2 + (size_t)(kc + 1) * 8192 +
                                            (wave * 64 + c * 16 + lm) * 32 + lq * 8);
        }
        short8 afr = *(const short8*)&XA[lm * 264 + kc * 32 + lq * 8];
#pragma unroll
        for (int c = 0; c < 4; c++)
            acc[c] = __builtin_amdgcn_mfma_f32_16x16x32_bf16(afr, bcur[c], acc[c], 0, 0, 0);
#pragma unroll
        for (int c = 0; c < 4; c++) bcur[c] = bnext[c];
    }

    // epilogue 1: WHT[b][hd][n] f16, 8B packed stores
#pragma unroll
    for (int c = 0; c < 4; c++) {
        int hd = wave * 64 + c * 16 + lm;
        unsigned short w0 = __builtin_bit_cast(unsigned short, (_Float16)acc[c][0]);
        unsigned short w1 = __builtin_bit_cast(unsigned short, (_Float16)acc[c][1]);
        unsigned short w2 = __builtin_bit_cast(unsigned short, (_Float16)acc[c][2]);
        unsigned short w3 = __builtin_bit_cast(unsigned short, (_Float16)acc[c][3]);
        uint2 pk;
        pk.x = (unsigned)w0 | ((unsigned)w1 << 16);
        pk.y = (unsigned)w2 | ((unsigned)w3 << 16);
        *(uint2*)&WHT[((size_t)b * 256 + hd) * 2048 + n0 + lq * 4] = pk;
    }
    // epilogue 2: s1/s2 -> S1/UH/VH
#pragma unroll
    for (int cp = 0; cp < 2; cp++) {
        int h = wave * 2 + cp;
        float a1l = AF[h * 64 + lm],      a1h = AF[h * 64 + 16 + lm];
        float a2l = AF[h * 64 + 32 + lm], a2h = AF[h * 64 + 48 + lm];
#pragma unroll
        for (int r = 0; r < 4; r++) {
            float s1p = acc[cp * 2][r] * a1l + acc[cp * 2 + 1][r] * a1h;
            float s2p = acc[cp * 2][r] * a2l + acc[cp * 2 + 1][r] * a2h;
#pragma unroll
            for (int off = 1; off <= 8; off <<= 1) {
                s1p += __shfl_xor(s1p, off);
                s2p += __shfl_xor(s2p, off);
            }
            if (lm == 0) {
                int bh = b * 8 + h, n = n0 + lq * 4 + r;
                S1[(size_t)bh * 2048 + n] = s1p;
                UH[(size_t)bh * 2048 + n] = (_Float16)exp2f(C1 * s2p);
                VH[(size_t)bh * 2048 + n] = (_Float16)exp2f(C2 * s2p);
            }
        }
    }
}

// ---- k3: R3 structure (256 thr, A+B frags, 4-buf LW) + UH/VH in LDS ------
// Inner loop is now pure LDS+VALU+MFMA: the 128 per-wave L2 round-trips for
// UH/VH are replaced by one 8KB prologue stage. LDS = 34816+35840+8192 =
// 78848 B -> 2 blocks/CU (grid-matched, 8 waves/CU).
__global__ __launch_bounds__(256) void k3_attn(
    const unsigned* __restrict__ bm32,
    const unsigned short* __restrict__ WHT,
    const float* __restrict__ S1,
    const _Float16* __restrict__ UH, const _Float16* __restrict__ VH,
    float* __restrict__ out) {
    __shared__ unsigned LM[4][32 * 68];            // per-wave 32-row bitmask (34816 B)
    __shared__ unsigned short LW[4][32 * 140];     // 4-buf [d][128j] (35840 B)
    __shared__ unsigned LU[1024], LV[1024];        // UH/VH rows for this bh (8192 B)

    // XCD-aware swizzle: group the 16 isup-blocks of one (b,h) on one XCD.
    int bid = blockIdx.x;                          // 512
    int bh = (bid & 7) + ((bid >> 7) << 3);
    int isup = (bid >> 3) & 15;
    int b = bh >> 3, h = bh & 7;
    int i0 = isup * 128;
    int t = threadIdx.x;
    int wave = t >> 6, lane = t & 63;
    int irow = lane & 15, quad = lane >> 4;
    int iw = i0 + wave * 32;                       // this wave's 32 i-rows

    // per-wave private bitmask staging (stride 68 dwords: 16B-aligned rows)
    {
        unsigned* lmp = LM[wave];
        const unsigned* src = bm32 + ((size_t)(b * N + iw)) * 64;
#pragma unroll 8
        for (int r = 0; r < 32; r++)
            lmp[r * 68 + lane] = src[(size_t)r * 64 + lane];
    }
    // UH/VH rows staged once: 16B/thread each (coalesced, 8KB total)
    {
        ((uint4*)LU)[t] = ((const uint4*)(UH + (size_t)bh * 2048))[t];
        ((uint4*)LV)[t] = ((const uint4*)(VH + (size_t)bh * 2048))[t];
    }

    const unsigned short* wsrc = WHT + ((size_t)b * 256 + h * 32) * 2048;
    int srow = t >> 3, sseg = (t & 7) * 16;        // staging map: 32B/thread/chunk

    // prologue: stage chunks 0,1
    {
        const unsigned short* g0 = wsrc + (size_t)srow * 2048 + sseg;
        union { short8 v; s4 q[2]; } a0, c0, a1, c1;
        a0.v = *(const short8*)(g0);
        c0.v = *(const short8*)(g0 + 8);
        a1.v = *(const short8*)(g0 + 128);
        c1.v = *(const short8*)(g0 + 136);
        unsigned short* d0 = &LW[0][srow * 140 + sseg];
        *(s4*)(d0) = a0.q[0]; *(s4*)(d0 + 4) = a0.q[1];
        *(s4*)(d0 + 8) = c0.q[0]; *(s4*)(d0 + 12) = c0.q[1];
        unsigned short* d1 = &LW[1][srow * 140 + sseg];
        *(s4*)(d1) = a1.q[0]; *(s4*)(d1 + 4) = a1.q[1];
        *(s4*)(d1 + 8) = c1.q[0]; *(s4*)(d1 + 12) = c1.q[1];
    }

    float s1A = S1[(size_t)bh * 2048 + iw + irow];
    float s1B = S1[(size_t)bh * 2048 + iw + 16 + irow];
    unsigned ci2A = dup16f(exp2f((C2 - C1) * s1A));
    unsigned ci2B = dup16f(exp2f((C2 - C1) * s1B));

    union { h8 v; unsigned u[4]; } ones;
    ones.u[0] = ones.u[1] = ones.u[2] = ones.u[3] = 0x3C003C00u;

    const unsigned MUL = 0x40008000u;              // bit-deposit multiplier (SGPR)

    f32x4 aA0 = {0,0,0,0}, aA1 = {0,0,0,0}, aAL = {0,0,0,0};
    f32x4 aB0 = {0,0,0,0}, aB1 = {0,0,0,0}, aBL = {0,0,0,0};
    __syncthreads();

    for (int g = 0; g < 8; g++) {
        // prefetch chunks 2g+2, 2g+3 (consumed after 2 chunks of compute)
        union { short8 v; s4 q[2]; } pa0, pc0, pa1, pc1;
        if (g < 7) {
            const unsigned short* g0 = wsrc + (size_t)srow * 2048 + (2 * g + 2) * 128 + sseg;
            pa0.v = *(const short8*)(g0);
            pc0.v = *(const short8*)(g0 + 8);
            pa1.v = *(const short8*)(g0 + 128);
            pc1.v = *(const short8*)(g0 + 136);
        }
        const unsigned* lmw = LM[wave];
#pragma unroll
        for (int ci = 0; ci < 2; ci++) {
            int cc = 2 * g + ci;
            const unsigned short* lwp = LW[cc & 3];
            // all 4 mask words per frag-row for this chunk: one b128 LDS read
            uint4 mkqA = *(const uint4*)&lmw[irow * 68 + cc * 4];
            uint4 mkqB = *(const uint4*)&lmw[(16 + irow) * 68 + cc * 4];
            unsigned mkwA[4] = { mkqA.x, mkqA.y, mkqA.z, mkqA.w };
            unsigned mkwB[4] = { mkqB.x, mkqB.y, mkqB.z, mkqB.w };
#pragma unroll
            for (int ks = 0; ks < 4; ks++) {
                int jl = ks * 32 + quad * 8;
                int jg = cc * 128 + jl;
                uint4 uw = *(const uint4*)&LU[jg >> 1];   // broadcast within quad
                uint4 vw = *(const uint4*)&LV[jg >> 1];
                unsigned mkA = mkwA[ks] >> (quad * 8);
                unsigned mkB = mkwB[ks] >> (quad * 8);
                unsigned mA0 = bits2mask(mkA,      MUL);
                unsigned mA1 = bits2mask(mkA >> 2, MUL);
                unsigned mA2 = bits2mask(mkA >> 4, MUL);
                unsigned mA3 = bits2mask(mkA >> 6, MUL);
                unsigned mB0 = bits2mask(mkB,      MUL);
                unsigned mB1 = bits2mask(mkB >> 2, MUL);
                unsigned mB2 = bits2mask(mkB >> 4, MUL);
                unsigned mB3 = bits2mask(mkB >> 6, MUL);
                union { h8 v; unsigned u[4]; } afA, afB;
                afA.u[0] = h2max(uw.x, h2mul(ci2A, vw.x)) & mA0;
                afA.u[1] = h2max(uw.y, h2mul(ci2A, vw.y)) & mA1;
                afA.u[2] = h2max(uw.z, h2mul(ci2A, vw.z)) & mA2;
                afA.u[3] = h2max(uw.w, h2mul(ci2A, vw.w)) & mA3;
                afB.u[0] = h2max(uw.x, h2mul(ci2B, vw.x)) & mB0;
                afB.u[1] = h2max(uw.y, h2mul(ci2B, vw.y)) & mB1;
                afB.u[2] = h2max(uw.z, h2mul(ci2B, vw.z)) & mB2;
                afB.u[3] = h2max(uw.w, h2mul(ci2B, vw.w)) & mB3;
                union { short8 v; s4 q[2]; } bf0, bf1;
                bf0.q[0] = *(const s4*)&lwp[irow * 140 + jl];
                bf0.q[1] = *(const s4*)&lwp[irow * 140 + jl + 4];
                bf1.q[0] = *(const s4*)&lwp[(16 + irow) * 140 + jl];
                bf1.q[1] = *(const s4*)&lwp[(16 + irow) * 140 + jl + 4];
                h8 b0 = __builtin_bit_cast(h8, bf0.v);
                h8 b1 = __builtin_bit_cast(h8, bf1.v);
                aA0 = __builtin_amdgcn_mfma_f32_16x16x32_f16(afA.v, b0, aA0, 0, 0, 0);
                aA1 = __builtin_amdgcn_mfma_f32_16x16x32_f16(afA.v, b1, aA1, 0, 0, 0);
                aAL = __builtin_amdgcn_mfma_f32_16x16x32_f16(afA.v, ones.v, aAL, 0, 0, 0);
                aB0 = __builtin_amdgcn_mfma_f32_16x16x32_f16(afB.v, b0, aB0, 0, 0, 0);
                aB1 = __builtin_amdgcn_mfma_f32_16x16x32_f16(afB.v, b1, aB1, 0, 0, 0);
                aBL = __builtin_amdgcn_mfma_f32_16x16x32_f16(afB.v, ones.v, aBL, 0, 0, 0);
            }
        }
        if (g < 7) {
            // write into buffers last read in group g-1 (all waves past that barrier)
            unsigned short* d0 = &LW[(2 * g + 2) & 3][srow * 140 + sseg];
            *(s4*)(d0) = pa0.q[0]; *(s4*)(d0 + 4) = pa0.q[1];
            *(s4*)(d0 + 8) = pc0.q[0]; *(s4*)(d0 + 12) = pc0.q[1];
            unsigned short* d1 = &LW[(2 * g + 3) & 3][srow * 140 + sseg];
            *(s4*)(d1) = pa1.q[0]; *(s4*)(d1 + 4) = pa1.q[1];
            *(s4*)(d1 + 8) = pc1.q[0]; *(s4*)(d1 + 12) = pc1.q[1];
        }
        __syncthreads();
    }

#pragma unroll
    for (int r = 0; r < 4; r++) {
        float lA = aAL[r], lB = aBL[r];
        float rA = 1.0f / (lA > 0.f ? lA : 1.f);
        float rB = 1.0f / (lB > 0.f ? lB : 1.f);
        float vA0 = aA0[r] * rA, vA1 = aA1[r] * rA;
        float vB0 = aB0[r] * rB, vB1 = aB1[r] * rB;
        vA0 = vA0 > 0.f ? vA0 : __expf(vA0) - 1.f;   // ELU
        vA1 = vA1 > 0.f ? vA1 : __expf(vA1) - 1.f;
        vB0 = vB0 > 0.f ? vB0 : __expf(vB0) - 1.f;
        vB1 = vB1 > 0.f ? vB1 : __expf(vB1) - 1.f;
        int iA = iw + quad * 4 + r, iB = iA + 16;
        size_t rbA = (size_t)(b * N + iA) * 256 + h * 32;
        size_t rbB = (size_t)(b * N + iB) * 256 + h * 32;
        out[rbA + irow] = vA0;
        out[rbA + 16 + irow] = vA1;
        out[rbB + irow] = vB0;
        out[rbB + 16 + irow] = vB1;
    }
}

extern "C" void kernel_launch(void* const* d_in, const int* in_sizes, int n_in,
                              void* d_out, int out_size, void* d_ws, size_t ws_size,
                              hipStream_t stream) {
    const void *xP = nullptr, *adjP = nullptr, *WP = nullptr, *aP = nullptr;
    for (int i = 0; i < n_in; i++) {
        switch (in_sizes[i]) {
            case SZ_X:   xP = d_in[i]; break;
            case SZ_ADJ: adjP = d_in[i]; break;
            case SZ_W:   WP = d_in[i]; break;
            case SZ_A:   aP = d_in[i]; break;
            default: break;
        }
    }
    if (!xP || !adjP || !WP || !aP) { xP = d_in[0]; adjP = d_in[1]; WP = d_in[2]; aP = d_in[3]; }
    float* out = (float*)d_out;

    char* ws = (char*)d_ws;
    unsigned short* WT2 = (unsigned short*)(ws);
    float* AF  = (float*)(ws + 131072);
    float* S1  = (float*)(ws + 133120);
    _Float16* UH = (_Float16*)(ws + 395264);
    _Float16* VH = (_Float16*)(ws + 526336);
    unsigned short* WHT = (unsigned short*)(ws + 657408);
    unsigned long long* BM = (unsigned long long*)(ws + 4851712);

    k0_prep<<<256, 256, 0, stream>>>((const float*)WP, (const float*)aP, WT2, AF);
    k2_fused<<<2560, 256, 0, stream>>>((const float*)xP, WT2, AF, WHT, S1, UH, VH,
                                       (const int*)adjP, BM);
    k3_attn<<<512, 256, 0, stream>>>((const unsigned*)BM, WHT, S1, UH, VH, out);
}

// Round 8
// 137.967 us; speedup vs baseline: 1.1075x; 1.0282x over previous
//
#include <hip/hip_runtime.h>
#include <hip/hip_bf16.h>

#define ALPHA 0.2f

typedef __attribute__((ext_vector_type(8))) short short8;
typedef __attribute__((ext_vector_type(4))) short s4;
typedef __attribute__((ext_vector_type(8))) _Float16 h8;
typedef __attribute__((ext_vector_type(2))) _Float16 h2v;
typedef __attribute__((ext_vector_type(4))) float f32x4;
typedef __attribute__((ext_vector_type(2))) short sh2;

static constexpr int B = 4, N = 2048, F = 256, H = 8, D = 32;
static constexpr int SZ_X = B * N * F, SZ_ADJ = B * N * N, SZ_W = H * F * D, SZ_A = H * 2 * D;
static const float C1 = 1.4426950408889634f;           // log2(e)
static const float C2 = ALPHA * 1.4426950408889634f;

// ws layout (bytes):
// 0        WT2  bf16 [kc=8][hd=256][32] 131072   (B-frag-contiguous W)
// 131072   AF   f32  [H][64]            2048
// 133120   S1   f32  [32][2048]         262144
// 395264   UH   f16  [32][2048]         131072
// 526336   VH   f16  [32][2048]         131072
// 657408   WHT  f16  [b][hd=256][2048]  4194304
// 4851712  BM   u64  [B*N*N/64]         2097152   total ~6.6 MB

__device__ __forceinline__ unsigned rne16(unsigned u) {
    return u + 0x7fffu + ((u >> 16) & 1u);
}
__device__ __forceinline__ unsigned pk_rne(float a, float b) {   // bf16 pair
    return __builtin_amdgcn_perm(rne16(__float_as_uint(b)),
                                 rne16(__float_as_uint(a)), 0x07060302u);
}
__device__ __forceinline__ unsigned h2mul(unsigned a, unsigned b) {
    h2v r = __builtin_bit_cast(h2v, a) * __builtin_bit_cast(h2v, b);
    return __builtin_bit_cast(unsigned, r);
}
__device__ __forceinline__ unsigned h2max(unsigned a, unsigned b) {
    h2v r = __builtin_elementwise_max(__builtin_bit_cast(h2v, a),
                                      __builtin_bit_cast(h2v, b));
    return __builtin_bit_cast(unsigned, r);
}
__device__ __forceinline__ unsigned dup16f(float x) {
    unsigned short w = __builtin_bit_cast(unsigned short, (_Float16)x);
    return (unsigned)w | ((unsigned)w << 16);
}
// bits (0,1) of mk -> {0xFFFF,0} half-masks: v_and + v_mul_lo + v_pk_ashrrev_i16
__device__ __forceinline__ unsigned bits2mask(unsigned mk, unsigned mulc) {
    unsigned w = (mk & 3u) * mulc;          // b0 -> bit 15 ; b1 -> bit 31
    sh2 s = __builtin_bit_cast(sh2, w);
    s = s >> 15;                            // smear each 16-bit half from its sign bit
    return __builtin_bit_cast(unsigned, s);
}

// ---- k0: W[h][f][d] -> WT2[f>>5][h*32+d][f&31] bf16; a -> AF --------------
__global__ void k0_prep(const float* __restrict__ Wp, const float* __restrict__ ap,
                        unsigned short* __restrict__ WT2, float* __restrict__ AF) {
    int bid = blockIdx.x;              // 256 = H*D
    int h = bid >> 5, d = bid & 31;
    int f = threadIdx.x;
    unsigned short v = (unsigned short)(rne16(__float_as_uint(Wp[(h * F + f) * D + d])) >> 16);
    WT2[(size_t)(f >> 5) * 8192 + (h * 32 + d) * 32 + (f & 31)] = v;
    if (d == 0 && f < 64) AF[h * 64 + f] = ap[h * 64 + f];
}

// ---- k2: fused {Wh MFMA blocks} + {adj->bitmask blocks}; role by bid%5 ----
__global__ __launch_bounds__(256, 4) void k2_fused(const float* __restrict__ x,
                                                   const unsigned short* __restrict__ WT2,
                                                   const float* __restrict__ AF,
                                                   unsigned short* __restrict__ WHT,
                                                   float* __restrict__ S1,
                                                   _Float16* __restrict__ UH,
                                                   _Float16* __restrict__ VH,
                                                   const int* __restrict__ adj,
                                                   unsigned long long* __restrict__ bm) {
    __shared__ unsigned short XA[16 * 264];   // [n][f] bf16, stride 264 (528B, /16 ok)
    int bid = blockIdx.x;                     // 2560 = 512 mfma + 2048 bitmask, interleaved
    int rr = bid % 5;
    int grp = bid / 5;
    int t = threadIdx.x;

    if (rr != 4) {
        // ---- bitmask role: 32 strips/wave, all 32 loads in flight ----
        int wid = (grp * 4 + rr) * 4 + (t >> 6);   // 8192 wids x 32 strips = 262144
        int lane = t & 63;
        size_t base = (size_t)wid * 32;
        const int* ap2 = adj + base * 64 + lane;
        int v0[16], v1[16];
#pragma unroll
        for (int s = 0; s < 16; s++) v0[s] = ap2[(size_t)s * 64];
#pragma unroll
        for (int s = 0; s < 16; s++) v1[s] = ap2[(size_t)(16 + s) * 64];
        unsigned long long m0[16];
#pragma unroll
        for (int s = 0; s < 16; s++) m0[s] = __ballot(v0[s] != 0);
        unsigned long long m1[16];
#pragma unroll
        for (int s = 0; s < 16; s++) m1[s] = __ballot(v1[s] != 0);
        if (lane == 0) {
#pragma unroll
            for (int s = 0; s < 16; s++) bm[base + s] = m0[s];
#pragma unroll
            for (int s = 0; s < 16; s++) bm[base + 16 + s] = m1[s];
        }
        return;
    }

    // ---- Wh MFMA role ----
    int b = grp >> 7;
    int n0 = (grp & 127) * 16;
    int wave = t >> 6, lane = t & 63;
    int lm = lane & 15, lq = lane >> 4;

    // stage XA coalesced: x fp32 -> bf16
#pragma unroll
    for (int q = 0; q < 4; q++) {
        int idx = q * 256 + t;
        int row = idx >> 6, c16 = idx & 63;
        f32x4 v = *(const f32x4*)(x + (size_t)(b * N + n0 + row) * F + c16 * 4);
        unsigned* dst = (unsigned*)&XA[row * 264 + c16 * 4];
        dst[0] = pk_rne(v[0], v[1]);
        dst[1] = pk_rne(v[2], v[3]);
    }

    // issue kc=0 B-frag loads before the barrier (independent of XA)
    short8 bcur[4], bnext[4];
#pragma unroll
    for (int c = 0; c < 4; c++)
        bcur[c] = *(const short8*)(WT2 + (size_t)(wave * 64 + c * 16 + lm) * 32 + lq * 8);
    __syncthreads();

    f32x4 acc[4] = {};
#pragma unroll
    for (int kc = 0; kc < 8; kc++) {
        if (kc < 7) {
#pragma unroll
            for (int c = 0; c < 4; c++)
                bnext[c] = *(const short8*)(WT2 + (size_t)(kc + 1) * 8192 +
                                            (wave * 64 + c * 16 + lm) * 32 + lq * 8);
        }
        short8 afr = *(const short8*)&XA[lm * 264 + kc * 32 + lq * 8];
#pragma unroll
        for (int c = 0; c < 4; c++)
            acc[c] = __builtin_amdgcn_mfma_f32_16x16x32_bf16(afr, bcur[c], acc[c], 0, 0, 0);
#pragma unroll
        for (int c = 0; c < 4; c++) bcur[c] = bnext[c];
    }

    // epilogue 1: WHT[b][hd][n] f16, 8B packed stores
#pragma unroll
    for (int c = 0; c < 4; c++) {
        int hd = wave * 64 + c * 16 + lm;
        unsigned short w0 = __builtin_bit_cast(unsigned short, (_Float16)acc[c][0]);
        unsigned short w1 = __builtin_bit_cast(unsigned short, (_Float16)acc[c][1]);
        unsigned short w2 = __builtin_bit_cast(unsigned short, (_Float16)acc[c][2]);
        unsigned short w3 = __builtin_bit_cast(unsigned short, (_Float16)acc[c][3]);
        uint2 pk;
        pk.x = (unsigned)w0 | ((unsigned)w1 << 16);
        pk.y = (unsigned)w2 | ((unsigned)w3 << 16);
        *(uint2*)&WHT[((size_t)b * 256 + hd) * 2048 + n0 + lq * 4] = pk;
    }
    // epilogue 2: s1/s2 -> S1/UH/VH
#pragma unroll
    for (int cp = 0; cp < 2; cp++) {
        int h = wave * 2 + cp;
        float a1l = AF[h * 64 + lm],      a1h = AF[h * 64 + 16 + lm];
        float a2l = AF[h * 64 + 32 + lm], a2h = AF[h * 64 + 48 + lm];
#pragma unroll
        for (int r = 0; r < 4; r++) {
            float s1p = acc[cp * 2][r] * a1l + acc[cp * 2 + 1][r] * a1h;
            float s2p = acc[cp * 2][r] * a2l + acc[cp * 2 + 1][r] * a2h;
#pragma unroll
            for (int off = 1; off <= 8; off <<= 1) {
                s1p += __shfl_xor(s1p, off);
                s2p += __shfl_xor(s2p, off);
            }
            if (lm == 0) {
                int bh = b * 8 + h, n = n0 + lq * 4 + r;
                S1[(size_t)bh * 2048 + n] = s1p;
                UH[(size_t)bh * 2048 + n] = (_Float16)exp2f(C1 * s2p);
                VH[(size_t)bh * 2048 + n] = (_Float16)exp2f(C2 * s2p);
            }
        }
    }
}

// ---- k3: R7 structure + chunk-level LDS read clustering -------------------
// Per chunk: ALL 26 LDS reads (2 mask b128 + 8 LU/LV b128 + 16 bf b64) are
// issued together into registers -> ONE lgkmcnt wait per chunk instead of
// ~6 dependent waits per ks. ks loop is then pure VALU+MFMA.
__global__ __launch_bounds__(256) void k3_attn(
    const unsigned* __restrict__ bm32,
    const unsigned short* __restrict__ WHT,
    const float* __restrict__ S1,
    const _Float16* __restrict__ UH, const _Float16* __restrict__ VH,
    float* __restrict__ out) {
    __shared__ unsigned LM[4][32 * 68];            // per-wave 32-row bitmask (34816 B)
    __shared__ unsigned short LW[4][32 * 140];     // 4-buf [d][128j] (35840 B)
    __shared__ unsigned LU[1024], LV[1024];        // UH/VH rows for this bh (8192 B)

    // XCD-aware swizzle: group the 16 isup-blocks of one (b,h) on one XCD.
    int bid = blockIdx.x;                          // 512
    int bh = (bid & 7) + ((bid >> 7) << 3);
    int isup = (bid >> 3) & 15;
    int b = bh >> 3, h = bh & 7;
    int i0 = isup * 128;
    int t = threadIdx.x;
    int wave = t >> 6, lane = t & 63;
    int irow = lane & 15, quad = lane >> 4;
    int iw = i0 + wave * 32;                       // this wave's 32 i-rows

    // per-wave private bitmask staging (stride 68 dwords: 16B-aligned rows)
    {
        unsigned* lmp = LM[wave];
        const unsigned* src = bm32 + ((size_t)(b * N + iw)) * 64;
#pragma unroll 8
        for (int r = 0; r < 32; r++)
            lmp[r * 68 + lane] = src[(size_t)r * 64 + lane];
    }
    // UH/VH rows staged once: 16B/thread each (coalesced, 8KB total)
    {
        ((uint4*)LU)[t] = ((const uint4*)(UH + (size_t)bh * 2048))[t];
        ((uint4*)LV)[t] = ((const uint4*)(VH + (size_t)bh * 2048))[t];
    }

    const unsigned short* wsrc = WHT + ((size_t)b * 256 + h * 32) * 2048;
    int srow = t >> 3, sseg = (t & 7) * 16;        // staging map: 32B/thread/chunk

    // prologue: stage chunks 0,1
    {
        const unsigned short* g0 = wsrc + (size_t)srow * 2048 + sseg;
        union { short8 v; s4 q[2]; } a0, c0, a1, c1;
        a0.v = *(const short8*)(g0);
        c0.v = *(const short8*)(g0 + 8);
        a1.v = *(const short8*)(g0 + 128);
        c1.v = *(const short8*)(g0 + 136);
        unsigned short* d0 = &LW[0][srow * 140 + sseg];
        *(s4*)(d0) = a0.q[0]; *(s4*)(d0 + 4) = a0.q[1];
        *(s4*)(d0 + 8) = c0.q[0]; *(s4*)(d0 + 12) = c0.q[1];
        unsigned short* d1 = &LW[1][srow * 140 + sseg];
        *(s4*)(d1) = a1.q[0]; *(s4*)(d1 + 4) = a1.q[1];
        *(s4*)(d1 + 8) = c1.q[0]; *(s4*)(d1 + 12) = c1.q[1];
    }

    float s1A = S1[(size_t)bh * 2048 + iw + irow];
    float s1B = S1[(size_t)bh * 2048 + iw + 16 + irow];
    unsigned ci2A = dup16f(exp2f((C2 - C1) * s1A));
    unsigned ci2B = dup16f(exp2f((C2 - C1) * s1B));

    union { h8 v; unsigned u[4]; } ones;
    ones.u[0] = ones.u[1] = ones.u[2] = ones.u[3] = 0x3C003C00u;

    const unsigned MUL = 0x40008000u;              // bit-deposit multiplier (SGPR)

    f32x4 aA0 = {0,0,0,0}, aA1 = {0,0,0,0}, aAL = {0,0,0,0};
    f32x4 aB0 = {0,0,0,0}, aB1 = {0,0,0,0}, aBL = {0,0,0,0};
    __syncthreads();

    for (int g = 0; g < 8; g++) {
        // prefetch chunks 2g+2, 2g+3 (consumed after 2 chunks of compute)
        union { short8 v; s4 q[2]; } pa0, pc0, pa1, pc1;
        if (g < 7) {
            const unsigned short* g0 = wsrc + (size_t)srow * 2048 + (2 * g + 2) * 128 + sseg;
            pa0.v = *(const short8*)(g0);
            pc0.v = *(const short8*)(g0 + 8);
            pa1.v = *(const short8*)(g0 + 128);
            pc1.v = *(const short8*)(g0 + 136);
        }
        const unsigned* lmw = LM[wave];
#pragma unroll
        for (int ci = 0; ci < 2; ci++) {
            int cc = 2 * g + ci;
            const unsigned short* lwp = LW[cc & 3];
            // ---- cluster ALL LDS reads for this chunk (26 independent) ----
            uint4 mkqA = *(const uint4*)&lmw[irow * 68 + cc * 4];
            uint4 mkqB = *(const uint4*)&lmw[(16 + irow) * 68 + cc * 4];
            uint4 uws[4], vws[4];
            s4 bf0a[4], bf0b[4], bf1a[4], bf1b[4];
#pragma unroll
            for (int ks = 0; ks < 4; ks++) {
                int jl = ks * 32 + quad * 8;
                uws[ks] = *(const uint4*)&LU[(cc * 128 + jl) >> 1];
                vws[ks] = *(const uint4*)&LV[(cc * 128 + jl) >> 1];
                bf0a[ks] = *(const s4*)&lwp[irow * 140 + jl];
                bf0b[ks] = *(const s4*)&lwp[irow * 140 + jl + 4];
                bf1a[ks] = *(const s4*)&lwp[(16 + irow) * 140 + jl];
                bf1b[ks] = *(const s4*)&lwp[(16 + irow) * 140 + jl + 4];
            }
            unsigned mkwA[4] = { mkqA.x, mkqA.y, mkqA.z, mkqA.w };
            unsigned mkwB[4] = { mkqB.x, mkqB.y, mkqB.z, mkqB.w };
            // ---- compute phase: pure VALU + MFMA, zero LDS ----
            __builtin_amdgcn_s_setprio(1);
#pragma unroll
            for (int ks = 0; ks < 4; ks++) {
                unsigned mkA = mkwA[ks] >> (quad * 8);
                unsigned mkB = mkwB[ks] >> (quad * 8);
                unsigned mA0 = bits2mask(mkA,      MUL);
                unsigned mA1 = bits2mask(mkA >> 2, MUL);
                unsigned mA2 = bits2mask(mkA >> 4, MUL);
                unsigned mA3 = bits2mask(mkA >> 6, MUL);
                unsigned mB0 = bits2mask(mkB,      MUL);
                unsigned mB1 = bits2mask(mkB >> 2, MUL);
                unsigned mB2 = bits2mask(mkB >> 4, MUL);
                unsigned mB3 = bits2mask(mkB >> 6, MUL);
                union { h8 v; unsigned u[4]; } afA, afB;
                afA.u[0] = h2max(uws[ks].x, h2mul(ci2A, vws[ks].x)) & mA0;
                afA.u[1] = h2max(uws[ks].y, h2mul(ci2A, vws[ks].y)) & mA1;
                afA.u[2] = h2max(uws[ks].z, h2mul(ci2A, vws[ks].z)) & mA2;
                afA.u[3] = h2max(uws[ks].w, h2mul(ci2A, vws[ks].w)) & mA3;
                afB.u[0] = h2max(uws[ks].x, h2mul(ci2B, vws[ks].x)) & mB0;
                afB.u[1] = h2max(uws[ks].y, h2mul(ci2B, vws[ks].y)) & mB1;
                afB.u[2] = h2max(uws[ks].z, h2mul(ci2B, vws[ks].z)) & mB2;
                afB.u[3] = h2max(uws[ks].w, h2mul(ci2B, vws[ks].w)) & mB3;
                union { short8 v; s4 q[2]; } bf0, bf1;
                bf0.q[0] = bf0a[ks]; bf0.q[1] = bf0b[ks];
                bf1.q[0] = bf1a[ks]; bf1.q[1] = bf1b[ks];
                h8 b0 = __builtin_bit_cast(h8, bf0.v);
                h8 b1 = __builtin_bit_cast(h8, bf1.v);
                aA0 = __builtin_amdgcn_mfma_f32_16x16x32_f16(afA.v, b0, aA0, 0, 0, 0);
                aA1 = __builtin_amdgcn_mfma_f32_16x16x32_f16(afA.v, b1, aA1, 0, 0, 0);
                aAL = __builtin_amdgcn_mfma_f32_16x16x32_f16(afA.v, ones.v, aAL, 0, 0, 0);
                aB0 = __builtin_amdgcn_mfma_f32_16x16x32_f16(afB.v, b0, aB0, 0, 0, 0);
                aB1 = __builtin_amdgcn_mfma_f32_16x16x32_f16(afB.v, b1, aB1, 0, 0, 0);
                aBL = __builtin_amdgcn_mfma_f32_16x16x32_f16(afB.v, ones.v, aBL, 0, 0, 0);
            }
            __builtin_amdgcn_s_setprio(0);
        }
        if (g < 7) {
            // write into buffers last read in group g-1 (all waves past that barrier)
            unsigned short* d0 = &LW[(2 * g + 2) & 3][srow * 140 + sseg];
            *(s4*)(d0) = pa0.q[0]; *(s4*)(d0 + 4) = pa0.q[1];
            *(s4*)(d0 + 8) = pc0.q[0]; *(s4*)(d0 + 12) = pc0.q[1];
            unsigned short* d1 = &LW[(2 * g + 3) & 3][srow * 140 + sseg];
            *(s4*)(d1) = pa1.q[0]; *(s4*)(d1 + 4) = pa1.q[1];
            *(s4*)(d1 + 8) = pc1.q[0]; *(s4*)(d1 + 12) = pc1.q[1];
        }
        __syncthreads();
    }

#pragma unroll
    for (int r = 0; r < 4; r++) {
        float lA = aAL[r], lB = aBL[r];
        float rA = 1.0f / (lA > 0.f ? lA : 1.f);
        float rB = 1.0f / (lB > 0.f ? lB : 1.f);
        float vA0 = aA0[r] * rA, vA1 = aA1[r] * rA;
        float vB0 = aB0[r] * rB, vB1 = aB1[r] * rB;
        vA0 = vA0 > 0.f ? vA0 : __expf(vA0) - 1.f;   // ELU
        vA1 = vA1 > 0.f ? vA1 : __expf(vA1) - 1.f;
        vB0 = vB0 > 0.f ? vB0 : __expf(vB0) - 1.f;
        vB1 = vB1 > 0.f ? vB1 : __expf(vB1) - 1.f;
        int iA = iw + quad * 4 + r, iB = iA + 16;
        size_t rbA = (size_t)(b * N + iA) * 256 + h * 32;
        size_t rbB = (size_t)(b * N + iB) * 256 + h * 32;
        out[rbA + irow] = vA0;
        out[rbA + 16 + irow] = vA1;
        out[rbB + irow] = vB0;
        out[rbB + 16 + irow] = vB1;
    }
}

extern "C" void kernel_launch(void* const* d_in, const int* in_sizes, int n_in,
                              void* d_out, int out_size, void* d_ws, size_t ws_size,
                              hipStream_t stream) {
    const void *xP = nullptr, *adjP = nullptr, *WP = nullptr, *aP = nullptr;
    for (int i = 0; i < n_in; i++) {
        switch (in_sizes[i]) {
            case SZ_X:   xP = d_in[i]; break;
            case SZ_ADJ: adjP = d_in[i]; break;
            case SZ_W:   WP = d_in[i]; break;
            case SZ_A:   aP = d_in[i]; break;
            default: break;
        }
    }
    if (!xP || !adjP || !WP || !aP) { xP = d_in[0]; adjP = d_in[1]; WP = d_in[2]; aP = d_in[3]; }
    float* out = (float*)d_out;

    char* ws = (char*)d_ws;
    unsigned short* WT2 = (unsigned short*)(ws);
    float* AF  = (float*)(ws + 131072);
    float* S1  = (float*)(ws + 133120);
    _Float16* UH = (_Float16*)(ws + 395264);
    _Float16* VH = (_Float16*)(ws + 526336);
    unsigned short* WHT = (unsigned short*)(ws + 657408);
    unsigned long long* BM = (unsigned long long*)(ws + 4851712);

    k0_prep<<<256, 256, 0, stream>>>((const float*)WP, (const float*)aP, WT2, AF);
    k2_fused<<<2560, 256, 0, stream>>>((const float*)xP, WT2, AF, WHT, S1, UH, VH,
                                       (const int*)adjP, BM);
    k3_attn<<<512, 256, 0, stream>>>((const unsigned*)BM, WHT, S1, UH, VH, out);
}